// Round 2
// baseline (4359.034 us; speedup 1.0000x reference)
//
#include <hip/hip_runtime.h>
#include <hip/hip_bf16.h>
#include <math.h>

#define N_NODES 50000
#define N_EDGES 800000
#define DIM 96
#define HEADS 4
#define HEAD_DIM 24
#define SLOPE 0.2f
#define LN_EPS 1e-5f

#define TB 384   // 6 waves; 4 nodes x 96 features
#define NB 4     // nodes per block-iteration

// ---------------------------------------------------------------------------
// Kernel A: h = x @ W  (staged W in LDS), plus per-(node,head) attention dots
// ---------------------------------------------------------------------------
__global__ __launch_bounds__(TB) void k_transform(
    const float* __restrict__ x, const float* __restrict__ W,
    const float* __restrict__ attS, const float* __restrict__ attD,
    float* __restrict__ h, float* __restrict__ asrc, float* __restrict__ adst)
{
    __shared__ float Wl[DIM * DIM];     // 36.9 KB
    __shared__ float xl[NB][DIM];
    __shared__ float hl[NB][DIM];
    __shared__ float attl[2][DIM];
    const int tid = threadIdx.x;
    for (int i = tid; i < DIM * DIM; i += TB) Wl[i] = W[i];
    if (tid < DIM) { attl[0][tid] = attS[tid]; attl[1][tid] = attD[tid]; }
    const int ln = tid / DIM, f = tid % DIM;

    for (int base = blockIdx.x * NB; base < N_NODES; base += gridDim.x * NB) {
        const int n = base + ln;
        __syncthreads();   // Wl ready (iter 0); hl consumers done (iter>0)
        xl[ln][f] = (n < N_NODES) ? x[n * DIM + f] : 0.f;
        __syncthreads();
        float acc = 0.f;
        #pragma unroll
        for (int k = 0; k < DIM; ++k) acc += xl[ln][k] * Wl[k * DIM + f];
        hl[ln][f] = acc;
        if (n < N_NODES) h[n * DIM + f] = acc;
        __syncthreads();
        if (tid < NB * HEADS) {
            const int l = tid / HEADS, hd = tid % HEADS;
            const int nn = base + l;
            if (nn < N_NODES) {
                float s = 0.f, d = 0.f;
                #pragma unroll
                for (int k = 0; k < HEAD_DIM; ++k) {
                    const float hv = hl[l][hd * HEAD_DIM + k];
                    s += hv * attl[0][hd * HEAD_DIM + k];
                    d += hv * attl[1][hd * HEAD_DIM + k];
                }
                asrc[nn * HEADS + hd] = s;
                adst[nn * HEADS + hd] = d;
            }
        }
    }
}

// ---------------------------------------------------------------------------
// Kernel B: initialize accumulators with the self-loop term (plain stores)
// ---------------------------------------------------------------------------
__global__ void k_init(const float* __restrict__ h, const float* __restrict__ asrc,
                       const float* __restrict__ adst, float* __restrict__ out,
                       float* __restrict__ denom)
{
    const int t = blockIdx.x * 256 + threadIdx.x;
    if (t >= N_NODES * DIM) return;
    const int n = t / DIM, f = t % DIM, hd = f / HEAD_DIM;
    float e = asrc[n * HEADS + hd] + adst[n * HEADS + hd];
    e = (e > 0.f) ? e : SLOPE * e;
    const float w = __expf(e);
    out[t] = w * h[t];
    if ((f % HEAD_DIM) == 0) denom[n * HEADS + hd] = w;
}

// ---------------------------------------------------------------------------
// Kernel C: per-(edge,head) exp(leaky(logit)) -> atomic scatter-aggregate
// edge_index arrives as int32 (harness converts integer inputs to int).
// ---------------------------------------------------------------------------
__global__ void k_edges(const int* __restrict__ ei,
                        const float* __restrict__ h, const float* __restrict__ asrc,
                        const float* __restrict__ adst,
                        float* __restrict__ out, float* __restrict__ denom)
{
    const int t = blockIdx.x * 256 + threadIdx.x;
    if (t >= N_EDGES * HEADS) return;
    const int e = t >> 2, hd = t & 3;
    const int s = ei[e];
    const int d = ei[N_EDGES + e];
    if ((unsigned)s >= N_NODES || (unsigned)d >= N_NODES) return;  // safety
    float logit = asrc[s * HEADS + hd] + adst[d * HEADS + hd];
    logit = (logit > 0.f) ? logit : SLOPE * logit;
    const float w = __expf(logit);
    atomicAdd(&denom[d * HEADS + hd], w);
    const float* __restrict__ hs = h + (size_t)s * DIM + hd * HEAD_DIM;
    float* od = out + (size_t)d * DIM + hd * HEAD_DIM;
    #pragma unroll
    for (int k = 0; k < HEAD_DIM; ++k) atomicAdd(&od[k], w * hs[k]);
}

// ---------------------------------------------------------------------------
// Kernel D: alpha-normalize + gat_bias, proj (out @ PW^T + pb), residual, LN
// ---------------------------------------------------------------------------
__global__ __launch_bounds__(TB) void k_finalize(
    const float* __restrict__ x, const float* __restrict__ PW,
    const float* __restrict__ pb, const float* __restrict__ gb,
    const float* __restrict__ lng, const float* __restrict__ lnb,
    float* __restrict__ out, const float* __restrict__ denom)
{
    __shared__ float PWl[DIM * (DIM + 1)];   // padded stride 97: no bank conflict
    __shared__ float g[NB][DIM];
    __shared__ float red[NB][DIM];
    __shared__ float mbuf[NB], vbuf[NB];
    const int tid = threadIdx.x;
    for (int i = tid; i < DIM * DIM; i += TB)
        PWl[(i / DIM) * (DIM + 1) + (i % DIM)] = PW[i];
    const int ln = tid / DIM, f = tid % DIM;

    for (int base = blockIdx.x * NB; base < N_NODES; base += gridDim.x * NB) {
        const int n = base + ln;
        __syncthreads();   // PWl ready (iter 0); prev-iter shared reads done
        float xv = 0.f;
        if (n < N_NODES) {
            const float acc = out[n * DIM + f];
            const float dn  = denom[n * HEADS + f / HEAD_DIM];
            g[ln][f] = acc / dn + gb[f];
            xv = x[n * DIM + f];
        } else g[ln][f] = 0.f;
        __syncthreads();
        float proj = pb[f];
        #pragma unroll
        for (int k = 0; k < DIM; ++k) proj += g[ln][k] * PWl[f * (DIM + 1) + k];
        const float z = xv + proj;
        // mean over 96
        red[ln][f] = z;                  __syncthreads();
        if (f < 48) red[ln][f] += red[ln][f + 48]; __syncthreads();
        if (f < 24) red[ln][f] += red[ln][f + 24]; __syncthreads();
        if (f < 12) red[ln][f] += red[ln][f + 12]; __syncthreads();
        if (f < 6)  red[ln][f] += red[ln][f + 6];  __syncthreads();
        if (f == 0)
            mbuf[ln] = (red[ln][0] + red[ln][1] + red[ln][2] +
                        red[ln][3] + red[ln][4] + red[ln][5]) * (1.f / DIM);
        __syncthreads();
        const float mu = mbuf[ln];
        const float dz = z - mu;
        // var over 96
        red[ln][f] = dz * dz;            __syncthreads();
        if (f < 48) red[ln][f] += red[ln][f + 48]; __syncthreads();
        if (f < 24) red[ln][f] += red[ln][f + 24]; __syncthreads();
        if (f < 12) red[ln][f] += red[ln][f + 12]; __syncthreads();
        if (f < 6)  red[ln][f] += red[ln][f + 6];  __syncthreads();
        if (f == 0)
            vbuf[ln] = (red[ln][0] + red[ln][1] + red[ln][2] +
                        red[ln][3] + red[ln][4] + red[ln][5]) * (1.f / DIM);
        __syncthreads();
        const float var = vbuf[ln];
        if (n < N_NODES)
            out[n * DIM + f] = lng[f] * dz * rsqrtf(var + LN_EPS) + lnb[f];
    }
}

// ---------------------------------------------------------------------------
extern "C" void kernel_launch(void* const* d_in, const int* in_sizes, int n_in,
                              void* d_out, int out_size, void* d_ws, size_t ws_size,
                              hipStream_t stream)
{
    const float* x    = (const float*)d_in[0];
    const int*   ei   = (const int*)d_in[1];     // [2, E] int32 (harness-converted)
    const float* W    = (const float*)d_in[2];
    const float* attS = (const float*)d_in[3];
    const float* attD = (const float*)d_in[4];
    const float* gb   = (const float*)d_in[5];
    const float* PW   = (const float*)d_in[6];
    const float* pb   = (const float*)d_in[7];
    const float* lng  = (const float*)d_in[8];
    const float* lnb  = (const float*)d_in[9];
    float* out = (float*)d_out;

    char* ws = (char*)d_ws;
    float* h     = (float*)ws;                                   // N*96 f32
    float* asrc  = (float*)(ws + (size_t)N_NODES * DIM * 4);     // N*4
    float* adst  = asrc + N_NODES * HEADS;                       // N*4
    float* denom = adst + N_NODES * HEADS;                       // N*4

    k_transform<<<768, TB, 0, stream>>>(x, W, attS, attD, h, asrc, adst);
    k_init<<<(N_NODES * DIM + 255) / 256, 256, 0, stream>>>(h, asrc, adst, out, denom);
    k_edges<<<(N_EDGES * HEADS + 255) / 256, 256, 0, stream>>>(ei, h, asrc, adst, out, denom);
    k_finalize<<<768, TB, 0, stream>>>(x, PW, pb, gb, lng, lnb, out, denom);
}

// Round 3
// 418.693 us; speedup vs baseline: 10.4110x; 10.4110x over previous
//
#include <hip/hip_runtime.h>
#include <hip/hip_bf16.h>
#include <math.h>

#define N_NODES 50000
#define N_EDGES 800000
#define DIM 96
#define HEADS 4
#define HEAD_DIM 24
#define SLOPE 0.2f
#define LN_EPS 1e-5f

#define TB 384   // 6 waves; 4 nodes x 96 features
#define NB 4     // nodes per block-iteration

// ---------------------------------------------------------------------------
// Kernel A: h = x @ W  (staged W in LDS), plus per-(node,head) attention dots
// ---------------------------------------------------------------------------
__global__ __launch_bounds__(TB) void k_transform(
    const float* __restrict__ x, const float* __restrict__ W,
    const float* __restrict__ attS, const float* __restrict__ attD,
    float* __restrict__ h, float* __restrict__ asrc, float* __restrict__ adst)
{
    __shared__ float Wl[DIM * DIM];     // 36.9 KB
    __shared__ float xl[NB][DIM];
    __shared__ float hl[NB][DIM];
    __shared__ float attl[2][DIM];
    const int tid = threadIdx.x;
    for (int i = tid; i < DIM * DIM; i += TB) Wl[i] = W[i];
    if (tid < DIM) { attl[0][tid] = attS[tid]; attl[1][tid] = attD[tid]; }
    const int ln = tid / DIM, f = tid % DIM;

    for (int base = blockIdx.x * NB; base < N_NODES; base += gridDim.x * NB) {
        const int n = base + ln;
        __syncthreads();
        xl[ln][f] = (n < N_NODES) ? x[n * DIM + f] : 0.f;
        __syncthreads();
        float acc = 0.f;
        #pragma unroll
        for (int k = 0; k < DIM; ++k) acc += xl[ln][k] * Wl[k * DIM + f];
        hl[ln][f] = acc;
        if (n < N_NODES) h[n * DIM + f] = acc;
        __syncthreads();
        if (tid < NB * HEADS) {
            const int l = tid / HEADS, hd = tid % HEADS;
            const int nn = base + l;
            if (nn < N_NODES) {
                float s = 0.f, d = 0.f;
                #pragma unroll
                for (int k = 0; k < HEAD_DIM; ++k) {
                    const float hv = hl[l][hd * HEAD_DIM + k];
                    s += hv * attl[0][hd * HEAD_DIM + k];
                    d += hv * attl[1][hd * HEAD_DIM + k];
                }
                asrc[nn * HEADS + hd] = s;
                adst[nn * HEADS + hd] = d;
            }
        }
    }
}

// ---------------------------------------------------------------------------
// CSR build: histogram -> scan -> scatter (dst-sorted src ids)
// ---------------------------------------------------------------------------
__global__ void k_hist(const int* __restrict__ ei, int* __restrict__ counts)
{
    const int e = blockIdx.x * 256 + threadIdx.x;
    if (e >= N_EDGES) return;
    const int d = ei[N_EDGES + e];
    if ((unsigned)d < N_NODES) atomicAdd(&counts[d], 1);
}

__global__ __launch_bounds__(1024) void k_scan(const int* __restrict__ counts,
                                               int* __restrict__ offsets,
                                               int* __restrict__ cursor)
{
    __shared__ int sums[1024];
    const int t = threadIdx.x;
    const int chunk = (N_NODES + 1023) / 1024;           // 49
    const int lo = t * chunk;
    const int hi = (lo + chunk < N_NODES) ? lo + chunk : N_NODES;
    int s = 0;
    for (int i = lo; i < hi; ++i) s += counts[i];
    sums[t] = s;
    __syncthreads();
    for (int off = 1; off < 1024; off <<= 1) {           // Hillis-Steele inclusive
        int v = (t >= off) ? sums[t - off] : 0;
        __syncthreads();
        sums[t] += v;
        __syncthreads();
    }
    int run = (t == 0) ? 0 : sums[t - 1];                // exclusive prefix
    for (int i = lo; i < hi; ++i) {
        offsets[i] = run; cursor[i] = run; run += counts[i];
    }
    if (t == 1023) offsets[N_NODES] = run;               // == E
}

__global__ void k_scatter(const int* __restrict__ ei, int* __restrict__ cursor,
                          int* __restrict__ ssrc)
{
    const int e = blockIdx.x * 256 + threadIdx.x;
    if (e >= N_EDGES) return;
    const int s = ei[e], d = ei[N_EDGES + e];
    if ((unsigned)s >= N_NODES || (unsigned)d >= N_NODES) return;
    const int pos = atomicAdd(&cursor[d], 1);
    ssrc[pos] = s;
}

// ---------------------------------------------------------------------------
// Kernel C': gather-aggregate. One wave per dst node. Lane l owns features
// l and 64+l (l<32). No f32 atomics; denominators accumulate per-lane.
// Output: normalized GAT output + gat_bias.
// ---------------------------------------------------------------------------
__global__ __launch_bounds__(256) void k_aggregate(
    const int* __restrict__ offsets, const int* __restrict__ ssrc,
    const float* __restrict__ h, const float* __restrict__ asrc,
    const float* __restrict__ adst, const float* __restrict__ gb,
    float* __restrict__ out)
{
    const int wid  = (blockIdx.x * 256 + threadIdx.x) >> 6;
    const int lane = threadIdx.x & 63;
    if (wid >= N_NODES) return;
    const int d = wid;
    const bool has2 = (lane < 32);
    const int f0 = lane, f1 = 64 + lane;
    const int hd0 = f0 / HEAD_DIM;
    const int hd1 = has2 ? f1 / HEAD_DIM : 0;
    const float ad0 = adst[d * HEADS + hd0];
    const float ad1 = adst[d * HEADS + hd1];

    const int rs = offsets[d], re = offsets[d + 1];
    const int deg = re - rs;
    // coalesced pre-load of up to 64 src ids, broadcast later via shfl
    const int sv = (lane < deg) ? ssrc[rs + lane] : 0;
    const int cnt = deg + 1;                       // +1 for self-loop (i==0)

    float acc0 = 0.f, acc1 = 0.f, ds0 = 0.f, ds1 = 0.f;

    // software pipeline: stage A holds loads for iteration i
    int sA = d;                                    // i = 0: self-loop
    float a0A = asrc[sA * HEADS + hd0];
    float a1A = has2 ? asrc[sA * HEADS + hd1] : 0.f;
    float h0A = h[(size_t)sA * DIM + f0];
    float h1A = has2 ? h[(size_t)sA * DIM + f1] : 0.f;

    for (int i = 0; i < cnt; ++i) {
        int sB = 0; float a0B = 0.f, a1B = 0.f, h0B = 0.f, h1B = 0.f;
        if (i + 1 < cnt) {
            const int j = i;                       // edge index for iter i+1
            sB = (j < 64) ? __shfl(sv, j) : ssrc[rs + j];
            a0B = asrc[sB * HEADS + hd0];
            a1B = has2 ? asrc[sB * HEADS + hd1] : 0.f;
            h0B = h[(size_t)sB * DIM + f0];
            h1B = has2 ? h[(size_t)sB * DIM + f1] : 0.f;
        }
        float l0 = a0A + ad0; l0 = (l0 > 0.f) ? l0 : SLOPE * l0;
        const float w0 = __expf(l0);
        acc0 += w0 * h0A; ds0 += w0;
        if (has2) {
            float l1 = a1A + ad1; l1 = (l1 > 0.f) ? l1 : SLOPE * l1;
            const float w1 = __expf(l1);
            acc1 += w1 * h1A; ds1 += w1;
        }
        sA = sB; a0A = a0B; a1A = a1B; h0A = h0B; h1A = h1B;
    }

    out[(size_t)d * DIM + f0] = acc0 / ds0 + gb[f0];
    if (has2) out[(size_t)d * DIM + f1] = acc1 / ds1 + gb[f1];
}

// ---------------------------------------------------------------------------
// Kernel D: proj (g @ PW^T + pb), residual, LayerNorm (in-place on out)
// ---------------------------------------------------------------------------
__global__ __launch_bounds__(TB) void k_finalize(
    const float* __restrict__ x, const float* __restrict__ PW,
    const float* __restrict__ pb,
    const float* __restrict__ lng, const float* __restrict__ lnb,
    float* __restrict__ out)
{
    __shared__ float PWl[DIM * (DIM + 1)];   // padded stride 97
    __shared__ float g[NB][DIM];
    __shared__ float red[NB][DIM];
    __shared__ float mbuf[NB], vbuf[NB];
    const int tid = threadIdx.x;
    for (int i = tid; i < DIM * DIM; i += TB)
        PWl[(i / DIM) * (DIM + 1) + (i % DIM)] = PW[i];
    const int ln = tid / DIM, f = tid % DIM;

    for (int base = blockIdx.x * NB; base < N_NODES; base += gridDim.x * NB) {
        const int n = base + ln;
        __syncthreads();
        float xv = 0.f;
        if (n < N_NODES) {
            g[ln][f] = out[n * DIM + f];
            xv = x[n * DIM + f];
        } else g[ln][f] = 0.f;
        __syncthreads();
        float proj = pb[f];
        #pragma unroll
        for (int k = 0; k < DIM; ++k) proj += g[ln][k] * PWl[f * (DIM + 1) + k];
        const float z = xv + proj;
        red[ln][f] = z;                  __syncthreads();
        if (f < 48) red[ln][f] += red[ln][f + 48]; __syncthreads();
        if (f < 24) red[ln][f] += red[ln][f + 24]; __syncthreads();
        if (f < 12) red[ln][f] += red[ln][f + 12]; __syncthreads();
        if (f < 6)  red[ln][f] += red[ln][f + 6];  __syncthreads();
        if (f == 0)
            mbuf[ln] = (red[ln][0] + red[ln][1] + red[ln][2] +
                        red[ln][3] + red[ln][4] + red[ln][5]) * (1.f / DIM);
        __syncthreads();
        const float mu = mbuf[ln];
        const float dz = z - mu;
        red[ln][f] = dz * dz;            __syncthreads();
        if (f < 48) red[ln][f] += red[ln][f + 48]; __syncthreads();
        if (f < 24) red[ln][f] += red[ln][f + 24]; __syncthreads();
        if (f < 12) red[ln][f] += red[ln][f + 12]; __syncthreads();
        if (f < 6)  red[ln][f] += red[ln][f + 6];  __syncthreads();
        if (f == 0)
            vbuf[ln] = (red[ln][0] + red[ln][1] + red[ln][2] +
                        red[ln][3] + red[ln][4] + red[ln][5]) * (1.f / DIM);
        __syncthreads();
        const float var = vbuf[ln];
        if (n < N_NODES)
            out[n * DIM + f] = lng[f] * dz * rsqrtf(var + LN_EPS) + lnb[f];
    }
}

// ---------------------------------------------------------------------------
extern "C" void kernel_launch(void* const* d_in, const int* in_sizes, int n_in,
                              void* d_out, int out_size, void* d_ws, size_t ws_size,
                              hipStream_t stream)
{
    const float* x    = (const float*)d_in[0];
    const int*   ei   = (const int*)d_in[1];     // [2, E] int32 (harness-converted)
    const float* W    = (const float*)d_in[2];
    const float* attS = (const float*)d_in[3];
    const float* attD = (const float*)d_in[4];
    const float* gb   = (const float*)d_in[5];
    const float* PW   = (const float*)d_in[6];
    const float* pb   = (const float*)d_in[7];
    const float* lng  = (const float*)d_in[8];
    const float* lnb  = (const float*)d_in[9];
    float* out = (float*)d_out;

    char* ws = (char*)d_ws;
    float* h       = (float*)ws;                                 // N*96 f32
    float* asrc    = (float*)(ws + (size_t)N_NODES * DIM * 4);   // N*4
    float* adst    = asrc + N_NODES * HEADS;                     // N*4
    int*   counts  = (int*)(adst + N_NODES * HEADS);             // N
    int*   offsets = counts + N_NODES;                           // N+1
    int*   cursor  = offsets + N_NODES + 1;                      // N
    int*   ssrc    = cursor + N_NODES;                           // E

    hipMemsetAsync(counts, 0, N_NODES * sizeof(int), stream);
    k_hist   <<<(N_EDGES + 255) / 256, 256, 0, stream>>>(ei, counts);
    k_scan   <<<1, 1024, 0, stream>>>(counts, offsets, cursor);
    k_scatter<<<(N_EDGES + 255) / 256, 256, 0, stream>>>(ei, cursor, ssrc);
    k_transform<<<768, TB, 0, stream>>>(x, W, attS, attD, h, asrc, adst);
    k_aggregate<<<(N_NODES * 64 + 255) / 256, 256, 0, stream>>>(offsets, ssrc, h, asrc, adst, gb, out);
    k_finalize<<<768, TB, 0, stream>>>(x, PW, pb, lng, lnb, out);
}

// Round 4
// 316.531 us; speedup vs baseline: 13.7713x; 1.3228x over previous
//
#include <hip/hip_runtime.h>
#include <hip/hip_bf16.h>
#include <math.h>

#define N_NODES 50000
#define N_EDGES 800000
#define DIM 96
#define HEADS 4
#define HEAD_DIM 24
#define SLOPE 0.2f
#define LN_EPS 1e-5f

#define TB 384   // 6 waves; 4 nodes x 96 features
#define NB 4     // nodes per block-iteration

#define SCAN_BLK 512
#define SCAN_NB ((N_NODES + SCAN_BLK - 1) / SCAN_BLK)   // 98

// ---------------------------------------------------------------------------
// Kernel A: h = x @ W  (staged W in LDS), plus per-(node,head) attention dots
// ---------------------------------------------------------------------------
__global__ __launch_bounds__(TB) void k_transform(
    const float* __restrict__ x, const float* __restrict__ W,
    const float* __restrict__ attS, const float* __restrict__ attD,
    float* __restrict__ h, float* __restrict__ asrc, float* __restrict__ adst)
{
    __shared__ float Wl[DIM * DIM];     // 36.9 KB
    __shared__ float xl[NB][DIM];
    __shared__ float hl[NB][DIM];
    __shared__ float attl[2][DIM];
    const int tid = threadIdx.x;
    for (int i = tid; i < DIM * DIM; i += TB) Wl[i] = W[i];
    if (tid < DIM) { attl[0][tid] = attS[tid]; attl[1][tid] = attD[tid]; }
    const int ln = tid / DIM, f = tid % DIM;

    for (int base = blockIdx.x * NB; base < N_NODES; base += gridDim.x * NB) {
        const int n = base + ln;
        __syncthreads();
        xl[ln][f] = (n < N_NODES) ? x[n * DIM + f] : 0.f;
        __syncthreads();
        float acc = 0.f;
        #pragma unroll
        for (int k = 0; k < DIM; ++k) acc += xl[ln][k] * Wl[k * DIM + f];
        hl[ln][f] = acc;
        if (n < N_NODES) h[n * DIM + f] = acc;
        __syncthreads();
        if (tid < NB * HEADS) {
            const int l = tid / HEADS, hd = tid % HEADS;
            const int nn = base + l;
            if (nn < N_NODES) {
                float s = 0.f, d = 0.f;
                #pragma unroll
                for (int k = 0; k < HEAD_DIM; ++k) {
                    const float hv = hl[l][hd * HEAD_DIM + k];
                    s += hv * attl[0][hd * HEAD_DIM + k];
                    d += hv * attl[1][hd * HEAD_DIM + k];
                }
                asrc[nn * HEADS + hd] = s;
                adst[nn * HEADS + hd] = d;
            }
        }
    }
}

// ---------------------------------------------------------------------------
// CSR build: histogram -> hierarchical scan -> scatter (dst-sorted src ids)
// ---------------------------------------------------------------------------
__global__ void k_hist(const int* __restrict__ ei, int* __restrict__ counts)
{
    const int e = blockIdx.x * 256 + threadIdx.x;
    if (e >= N_EDGES) return;
    const int d = ei[N_EDGES + e];
    if ((unsigned)d < N_NODES) atomicAdd(&counts[d], 1);
}

__global__ __launch_bounds__(SCAN_BLK) void k_scan_partial(
    const int* __restrict__ counts, int* __restrict__ bsum)
{
    __shared__ int red[SCAN_BLK];
    const int t = threadIdx.x;
    const int i = blockIdx.x * SCAN_BLK + t;
    red[t] = (i < N_NODES) ? counts[i] : 0;
    __syncthreads();
    #pragma unroll
    for (int off = SCAN_BLK / 2; off > 0; off >>= 1) {
        if (t < off) red[t] += red[t + off];
        __syncthreads();
    }
    if (t == 0) bsum[blockIdx.x] = red[0];
}

__global__ __launch_bounds__(128) void k_scan_bsums(
    const int* __restrict__ bsum, int* __restrict__ bpre, int* __restrict__ offsets)
{
    __shared__ int s[128];
    const int t = threadIdx.x;
    const int v = (t < SCAN_NB) ? bsum[t] : 0;
    s[t] = v;
    __syncthreads();
    #pragma unroll
    for (int off = 1; off < 128; off <<= 1) {
        const int u = (t >= off) ? s[t - off] : 0;
        __syncthreads();
        s[t] += u;
        __syncthreads();
    }
    if (t < SCAN_NB) bpre[t] = s[t] - v;          // exclusive block prefix
    if (t == 127) offsets[N_NODES] = s[127];      // total valid edges
}

__global__ __launch_bounds__(SCAN_BLK) void k_scan_final(
    const int* __restrict__ counts, const int* __restrict__ bpre,
    int* __restrict__ offsets, int* __restrict__ cursor)
{
    __shared__ int s[SCAN_BLK];
    const int t = threadIdx.x;
    const int i = blockIdx.x * SCAN_BLK + t;
    const int v = (i < N_NODES) ? counts[i] : 0;
    s[t] = v;
    __syncthreads();
    #pragma unroll
    for (int off = 1; off < SCAN_BLK; off <<= 1) {
        const int u = (t >= off) ? s[t - off] : 0;
        __syncthreads();
        s[t] += u;
        __syncthreads();
    }
    if (i < N_NODES) {
        const int ex = bpre[blockIdx.x] + s[t] - v;
        offsets[i] = ex;
        cursor[i] = ex;
    }
}

__global__ void k_scatter(const int* __restrict__ ei, int* __restrict__ cursor,
                          int* __restrict__ ssrc)
{
    const int e = blockIdx.x * 256 + threadIdx.x;
    if (e >= N_EDGES) return;
    const int s = ei[e], d = ei[N_EDGES + e];
    if ((unsigned)s >= N_NODES || (unsigned)d >= N_NODES) return;
    const int pos = atomicAdd(&cursor[d], 1);
    ssrc[pos] = s;
}

// ---------------------------------------------------------------------------
// Kernel C': gather-aggregate. One wave per dst node. Lane l owns features
// l and 64+l (l<32). No f32 atomics; denominators accumulate per-lane.
// Output: normalized GAT output + gat_bias.
// ---------------------------------------------------------------------------
__global__ __launch_bounds__(256) void k_aggregate(
    const int* __restrict__ offsets, const int* __restrict__ ssrc,
    const float* __restrict__ h, const float* __restrict__ asrc,
    const float* __restrict__ adst, const float* __restrict__ gb,
    float* __restrict__ out)
{
    const int wid  = (blockIdx.x * 256 + threadIdx.x) >> 6;
    const int lane = threadIdx.x & 63;
    if (wid >= N_NODES) return;
    const int d = wid;
    const bool has2 = (lane < 32);
    const int f0 = lane, f1 = 64 + lane;
    const int hd0 = f0 / HEAD_DIM;
    const int hd1 = has2 ? f1 / HEAD_DIM : 0;
    const float ad0 = adst[d * HEADS + hd0];
    const float ad1 = adst[d * HEADS + hd1];

    const int rs = offsets[d], re = offsets[d + 1];
    const int deg = re - rs;
    const int sv = (lane < deg) ? ssrc[rs + lane] : 0;   // coalesced preload
    const int cnt = deg + 1;                             // +1: self-loop (i==0)

    float acc0 = 0.f, acc1 = 0.f, ds0 = 0.f, ds1 = 0.f;

    int sA = d;                                          // i = 0: self-loop
    float a0A = asrc[sA * HEADS + hd0];
    float a1A = has2 ? asrc[sA * HEADS + hd1] : 0.f;
    float h0A = h[(size_t)sA * DIM + f0];
    float h1A = has2 ? h[(size_t)sA * DIM + f1] : 0.f;

    for (int i = 0; i < cnt; ++i) {
        int sB = 0; float a0B = 0.f, a1B = 0.f, h0B = 0.f, h1B = 0.f;
        if (i + 1 < cnt) {
            const int j = i;                             // edge for iter i+1
            sB = (j < 64) ? __shfl(sv, j) : ssrc[rs + j];
            a0B = asrc[sB * HEADS + hd0];
            a1B = has2 ? asrc[sB * HEADS + hd1] : 0.f;
            h0B = h[(size_t)sB * DIM + f0];
            h1B = has2 ? h[(size_t)sB * DIM + f1] : 0.f;
        }
        float l0 = a0A + ad0; l0 = (l0 > 0.f) ? l0 : SLOPE * l0;
        const float w0 = __expf(l0);
        acc0 += w0 * h0A; ds0 += w0;
        if (has2) {
            float l1 = a1A + ad1; l1 = (l1 > 0.f) ? l1 : SLOPE * l1;
            const float w1 = __expf(l1);
            acc1 += w1 * h1A; ds1 += w1;
        }
        sA = sB; a0A = a0B; a1A = a1B; h0A = h0B; h1A = h1B;
    }

    out[(size_t)d * DIM + f0] = acc0 / ds0 + gb[f0];
    if (has2) out[(size_t)d * DIM + f1] = acc1 / ds1 + gb[f1];
}

// ---------------------------------------------------------------------------
// Kernel D: proj (g @ PW^T + pb), residual, LayerNorm (in-place on out)
// ---------------------------------------------------------------------------
__global__ __launch_bounds__(TB) void k_finalize(
    const float* __restrict__ x, const float* __restrict__ PW,
    const float* __restrict__ pb,
    const float* __restrict__ lng, const float* __restrict__ lnb,
    float* __restrict__ out)
{
    __shared__ float PWl[DIM * (DIM + 1)];   // padded stride 97
    __shared__ float g[NB][DIM];
    __shared__ float red[NB][DIM];
    __shared__ float mbuf[NB], vbuf[NB];
    const int tid = threadIdx.x;
    for (int i = tid; i < DIM * DIM; i += TB)
        PWl[(i / DIM) * (DIM + 1) + (i % DIM)] = PW[i];
    const int ln = tid / DIM, f = tid % DIM;

    for (int base = blockIdx.x * NB; base < N_NODES; base += gridDim.x * NB) {
        const int n = base + ln;
        __syncthreads();
        float xv = 0.f;
        if (n < N_NODES) {
            g[ln][f] = out[n * DIM + f];
            xv = x[n * DIM + f];
        } else g[ln][f] = 0.f;
        __syncthreads();
        float proj = pb[f];
        #pragma unroll
        for (int k = 0; k < DIM; ++k) proj += g[ln][k] * PWl[f * (DIM + 1) + k];
        const float z = xv + proj;
        red[ln][f] = z;                  __syncthreads();
        if (f < 48) red[ln][f] += red[ln][f + 48]; __syncthreads();
        if (f < 24) red[ln][f] += red[ln][f + 24]; __syncthreads();
        if (f < 12) red[ln][f] += red[ln][f + 12]; __syncthreads();
        if (f < 6)  red[ln][f] += red[ln][f + 6];  __syncthreads();
        if (f == 0)
            mbuf[ln] = (red[ln][0] + red[ln][1] + red[ln][2] +
                        red[ln][3] + red[ln][4] + red[ln][5]) * (1.f / DIM);
        __syncthreads();
        const float mu = mbuf[ln];
        const float dz = z - mu;
        red[ln][f] = dz * dz;            __syncthreads();
        if (f < 48) red[ln][f] += red[ln][f + 48]; __syncthreads();
        if (f < 24) red[ln][f] += red[ln][f + 24]; __syncthreads();
        if (f < 12) red[ln][f] += red[ln][f + 12]; __syncthreads();
        if (f < 6)  red[ln][f] += red[ln][f + 6];  __syncthreads();
        if (f == 0)
            vbuf[ln] = (red[ln][0] + red[ln][1] + red[ln][2] +
                        red[ln][3] + red[ln][4] + red[ln][5]) * (1.f / DIM);
        __syncthreads();
        const float var = vbuf[ln];
        if (n < N_NODES)
            out[n * DIM + f] = lng[f] * dz * rsqrtf(var + LN_EPS) + lnb[f];
    }
}

// ---------------------------------------------------------------------------
extern "C" void kernel_launch(void* const* d_in, const int* in_sizes, int n_in,
                              void* d_out, int out_size, void* d_ws, size_t ws_size,
                              hipStream_t stream)
{
    const float* x    = (const float*)d_in[0];
    const int*   ei   = (const int*)d_in[1];     // [2, E] int32 (harness-converted)
    const float* W    = (const float*)d_in[2];
    const float* attS = (const float*)d_in[3];
    const float* attD = (const float*)d_in[4];
    const float* gb   = (const float*)d_in[5];
    const float* PW   = (const float*)d_in[6];
    const float* pb   = (const float*)d_in[7];
    const float* lng  = (const float*)d_in[8];
    const float* lnb  = (const float*)d_in[9];
    float* out = (float*)d_out;

    char* ws = (char*)d_ws;
    float* h       = (float*)ws;                                 // N*96 f32
    float* asrc    = (float*)(ws + (size_t)N_NODES * DIM * 4);   // N*4
    float* adst    = asrc + N_NODES * HEADS;                     // N*4
    int*   counts  = (int*)(adst + N_NODES * HEADS);             // N
    int*   offsets = counts + N_NODES;                           // N+1
    int*   cursor  = offsets + N_NODES + 1;                      // N
    int*   bsum    = cursor + N_NODES;                           // SCAN_NB
    int*   bpre    = bsum + SCAN_NB;                             // SCAN_NB
    int*   ssrc    = bpre + SCAN_NB;                             // E

    hipMemsetAsync(counts, 0, N_NODES * sizeof(int), stream);
    k_hist        <<<(N_EDGES + 255) / 256, 256, 0, stream>>>(ei, counts);
    k_scan_partial<<<SCAN_NB, SCAN_BLK, 0, stream>>>(counts, bsum);
    k_scan_bsums  <<<1, 128, 0, stream>>>(bsum, bpre, offsets);
    k_scan_final  <<<SCAN_NB, SCAN_BLK, 0, stream>>>(counts, bpre, offsets, cursor);
    k_scatter     <<<(N_EDGES + 255) / 256, 256, 0, stream>>>(ei, cursor, ssrc);
    k_transform   <<<768, TB, 0, stream>>>(x, W, attS, attD, h, asrc, adst);
    k_aggregate   <<<(N_NODES * 64 + 255) / 256, 256, 0, stream>>>(offsets, ssrc, h, asrc, adst, gb, out);
    k_finalize    <<<768, TB, 0, stream>>>(x, PW, pb, lng, lnb, out);
}

// Round 5
// 279.795 us; speedup vs baseline: 15.5794x; 1.1313x over previous
//
#include <hip/hip_runtime.h>
#include <hip/hip_bf16.h>
#include <math.h>

#define N_NODES 50000
#define N_EDGES 800000
#define DIM 96
#define HEADS 4
#define HEAD_DIM 24
#define SLOPE 0.2f
#define LN_EPS 1e-5f

#define GT 192        // threads for the two tiled GEMM kernels (3 waves)
#define TNODES 32     // nodes per tile
#define XPAD 100      // x/g tile row stride (400B: 16B-aligned, 4-way banks)
#define PWPAD 108     // PW tile row stride (432B: 16B-aligned, 3-way banks)

#define SCAN_BLK 512
#define SCAN_NB ((N_NODES + SCAN_BLK - 1) / SCAN_BLK)   // 98

// ---------------------------------------------------------------------------
// Kernel A: h = x @ W, 4x4 register tile per thread, float4 LDS reads.
// Also emits per-(node,head) attention dots.
// ---------------------------------------------------------------------------
__global__ __launch_bounds__(GT) void k_transform(
    const float* __restrict__ x, const float* __restrict__ W,
    const float* __restrict__ attS, const float* __restrict__ attD,
    float* __restrict__ h, float* __restrict__ asrc, float* __restrict__ adst)
{
    __shared__ float Wl[DIM][DIM];        // [k][f] 36.9 KB
    __shared__ float xl[TNODES][XPAD];    // 12.5 KB (reused as h-tile)
    __shared__ float attl[2][DIM];
    const int tid = threadIdx.x;
    for (int i = tid; i < DIM * DIM; i += GT) Wl[i / DIM][i % DIM] = W[i];
    if (tid < DIM) { attl[0][tid] = attS[tid]; attl[1][tid] = attD[tid]; }
    const int tf = tid % 24, tn = tid / 24;     // 24 feat-groups x 8 node-groups
    const int f0 = tf * 4, n0 = tn * 4;
    const int ntiles = (N_NODES + TNODES - 1) / TNODES;

    for (int tile = blockIdx.x; tile < ntiles; tile += gridDim.x) {
        const int base = tile * TNODES;
        __syncthreads();   // Wl ready (iter 0); xl consumers done (iter>0)
        for (int i = tid; i < TNODES * DIM; i += GT) {
            const int n = i / DIM, f = i % DIM, gn = base + n;
            xl[n][f] = (gn < N_NODES) ? x[(size_t)gn * DIM + f] : 0.f;
        }
        __syncthreads();
        float acc[4][4] = {};
        for (int k = 0; k < DIM; k += 4) {
            float4 xq[4], wq[4];
            #pragma unroll
            for (int a = 0; a < 4; ++a) xq[a] = *(const float4*)&xl[n0 + a][k];
            #pragma unroll
            for (int j = 0; j < 4; ++j) wq[j] = *(const float4*)&Wl[k + j][f0];
            #pragma unroll
            for (int a = 0; a < 4; ++a) {
                const float x0 = xq[a].x, x1 = xq[a].y, x2 = xq[a].z, x3 = xq[a].w;
                acc[a][0] += x0 * wq[0].x + x1 * wq[1].x + x2 * wq[2].x + x3 * wq[3].x;
                acc[a][1] += x0 * wq[0].y + x1 * wq[1].y + x2 * wq[2].y + x3 * wq[3].y;
                acc[a][2] += x0 * wq[0].z + x1 * wq[1].z + x2 * wq[2].z + x3 * wq[3].z;
                acc[a][3] += x0 * wq[0].w + x1 * wq[1].w + x2 * wq[2].w + x3 * wq[3].w;
            }
        }
        #pragma unroll
        for (int a = 0; a < 4; ++a) {
            const int gn = base + n0 + a;
            if (gn < N_NODES)
                *(float4*)&h[(size_t)gn * DIM + f0] =
                    make_float4(acc[a][0], acc[a][1], acc[a][2], acc[a][3]);
        }
        __syncthreads();   // all xl reads done -> reuse as h-tile
        #pragma unroll
        for (int a = 0; a < 4; ++a)
            *(float4*)&xl[n0 + a][f0] =
                make_float4(acc[a][0], acc[a][1], acc[a][2], acc[a][3]);
        __syncthreads();
        if (tid < TNODES * HEADS) {        // 128 threads: (node, head)
            const int l = tid >> 2, hd = tid & 3, gn = base + l;
            if (gn < N_NODES) {
                float s = 0.f, dd = 0.f;
                #pragma unroll
                for (int kk = 0; kk < HEAD_DIM; ++kk) {
                    const float hv = xl[l][hd * HEAD_DIM + kk];
                    s  += hv * attl[0][hd * HEAD_DIM + kk];
                    dd += hv * attl[1][hd * HEAD_DIM + kk];
                }
                asrc[gn * HEADS + hd] = s;
                adst[gn * HEADS + hd] = dd;
            }
        }
    }
}

// ---------------------------------------------------------------------------
// CSR build: histogram -> hierarchical scan -> scatter (dst-sorted src+dst)
// ---------------------------------------------------------------------------
__global__ void k_hist(const int* __restrict__ ei, int* __restrict__ counts)
{
    const int e = blockIdx.x * 256 + threadIdx.x;
    if (e >= N_EDGES) return;
    const int d = ei[N_EDGES + e];
    if ((unsigned)d < N_NODES) atomicAdd(&counts[d], 1);
}

__global__ __launch_bounds__(SCAN_BLK) void k_scan_partial(
    const int* __restrict__ counts, int* __restrict__ bsum)
{
    __shared__ int red[SCAN_BLK];
    const int t = threadIdx.x;
    const int i = blockIdx.x * SCAN_BLK + t;
    red[t] = (i < N_NODES) ? counts[i] : 0;
    __syncthreads();
    #pragma unroll
    for (int off = SCAN_BLK / 2; off > 0; off >>= 1) {
        if (t < off) red[t] += red[t + off];
        __syncthreads();
    }
    if (t == 0) bsum[blockIdx.x] = red[0];
}

__global__ __launch_bounds__(128) void k_scan_bsums(
    const int* __restrict__ bsum, int* __restrict__ bpre, int* __restrict__ offsets)
{
    __shared__ int s[128];
    const int t = threadIdx.x;
    const int v = (t < SCAN_NB) ? bsum[t] : 0;
    s[t] = v;
    __syncthreads();
    #pragma unroll
    for (int off = 1; off < 128; off <<= 1) {
        const int u = (t >= off) ? s[t - off] : 0;
        __syncthreads();
        s[t] += u;
        __syncthreads();
    }
    if (t < SCAN_NB) bpre[t] = s[t] - v;
    if (t == 127) offsets[N_NODES] = s[127];      // total valid edges
}

__global__ __launch_bounds__(SCAN_BLK) void k_scan_final(
    const int* __restrict__ counts, const int* __restrict__ bpre,
    int* __restrict__ offsets, int* __restrict__ cursor)
{
    __shared__ int s[SCAN_BLK];
    const int t = threadIdx.x;
    const int i = blockIdx.x * SCAN_BLK + t;
    const int v = (i < N_NODES) ? counts[i] : 0;
    s[t] = v;
    __syncthreads();
    #pragma unroll
    for (int off = 1; off < SCAN_BLK; off <<= 1) {
        const int u = (t >= off) ? s[t - off] : 0;
        __syncthreads();
        s[t] += u;
        __syncthreads();
    }
    if (i < N_NODES) {
        const int ex = bpre[blockIdx.x] + s[t] - v;
        offsets[i] = ex;
        cursor[i] = ex;
    }
}

__global__ void k_scatter(const int* __restrict__ ei, int* __restrict__ cursor,
                          int* __restrict__ ssrc, int* __restrict__ sdst)
{
    const int e = blockIdx.x * 256 + threadIdx.x;
    if (e >= N_EDGES) return;
    const int s = ei[e], d = ei[N_EDGES + e];
    if ((unsigned)s >= N_NODES || (unsigned)d >= N_NODES) return;
    const int pos = atomicAdd(&cursor[d], 1);
    ssrc[pos] = s;
    sdst[pos] = d;
}

// ---------------------------------------------------------------------------
// Per-edge attention weights, fully coalesced over sorted positions.
// ---------------------------------------------------------------------------
__global__ void k_weights(const int* __restrict__ ssrc, const int* __restrict__ sdst,
                          const int* __restrict__ offsets,
                          const float* __restrict__ asrc, const float* __restrict__ adst,
                          float* __restrict__ wsrt)
{
    const int p = blockIdx.x * 256 + threadIdx.x;
    if (p >= offsets[N_NODES]) return;
    const int s = ssrc[p], d = sdst[p];
    const float4 as = *(const float4*)&asrc[s * 4];
    const float4 ad = *(const float4*)&adst[d * 4];
    float l; float4 w;
    l = as.x + ad.x; l = (l > 0.f) ? l : SLOPE * l; w.x = __expf(l);
    l = as.y + ad.y; l = (l > 0.f) ? l : SLOPE * l; w.y = __expf(l);
    l = as.z + ad.z; l = (l > 0.f) ? l : SLOPE * l; w.z = __expf(l);
    l = as.w + ad.w; l = (l > 0.f) ? l : SLOPE * l; w.w = __expf(l);
    *(float4*)&wsrt[(size_t)p * 4] = w;
}

// ---------------------------------------------------------------------------
// Kernel C: gather-aggregate. One wave per dst node; weights preloaded.
// ---------------------------------------------------------------------------
__global__ __launch_bounds__(256) void k_aggregate(
    const int* __restrict__ offsets, const int* __restrict__ ssrc,
    const float* __restrict__ wsrt,
    const float* __restrict__ h, const float* __restrict__ asrc,
    const float* __restrict__ adst, const float* __restrict__ gb,
    float* __restrict__ out)
{
    const int wid  = (blockIdx.x * 256 + threadIdx.x) >> 6;
    const int lane = threadIdx.x & 63;
    if (wid >= N_NODES) return;
    const int d = wid;
    const bool has2 = (lane < 32);
    const int f0 = lane, f1 = 64 + lane;
    const int hd0 = f0 / HEAD_DIM;
    const int hd1 = has2 ? f1 / HEAD_DIM : 0;

    const int rs = offsets[d], re = offsets[d + 1];
    const int deg = re - rs;
    const int sv = (lane < deg) ? ssrc[rs + lane] : 0;   // coalesced preload
    const int cnt = deg + 1;                             // +1: self-loop (i==0)

    float acc0 = 0.f, acc1 = 0.f, ds0 = 0.f, ds1 = 0.f;

    // pipeline stage A = iteration 0 (self-loop; weight computed inline)
    float h0A = h[(size_t)d * DIM + f0];
    float h1A = has2 ? h[(size_t)d * DIM + f1] : 0.f;
    float l0 = asrc[d * HEADS + hd0] + adst[d * HEADS + hd0];
    l0 = (l0 > 0.f) ? l0 : SLOPE * l0;
    float w0A = __expf(l0);
    float w1A = 0.f;
    if (has2) {
        float l1 = asrc[d * HEADS + hd1] + adst[d * HEADS + hd1];
        l1 = (l1 > 0.f) ? l1 : SLOPE * l1;
        w1A = __expf(l1);
    }

    for (int i = 0; i < cnt; ++i) {
        float h0B = 0.f, h1B = 0.f, w0B = 0.f, w1B = 0.f;
        if (i + 1 < cnt) {
            const int j = i;                             // edge for iter i+1
            const int sB = (j < 64) ? __shfl(sv, j) : ssrc[rs + j];
            h0B = h[(size_t)sB * DIM + f0];
            h1B = has2 ? h[(size_t)sB * DIM + f1] : 0.f;
            const float* wp = wsrt + (size_t)(rs + j) * 4;
            w0B = wp[hd0];                               // same 16B line, broadcast
            w1B = has2 ? wp[hd1] : 0.f;
        }
        acc0 += w0A * h0A; ds0 += w0A;
        if (has2) { acc1 += w1A * h1A; ds1 += w1A; }
        h0A = h0B; h1A = h1B; w0A = w0B; w1A = w1B;
    }

    out[(size_t)d * DIM + f0] = acc0 / ds0 + gb[f0];
    if (has2) out[(size_t)d * DIM + f1] = acc1 / ds1 + gb[f1];
}

// ---------------------------------------------------------------------------
// Kernel D: proj (g @ PW^T + pb) 4x4-tiled, + residual + LayerNorm, in-place.
// ---------------------------------------------------------------------------
__global__ __launch_bounds__(GT) void k_finalize(
    const float* __restrict__ x, const float* __restrict__ PW,
    const float* __restrict__ pb, const float* __restrict__ lng,
    const float* __restrict__ lnb, float* __restrict__ out)
{
    __shared__ float PWl[DIM][PWPAD];     // [f][k] padded: 41.5 KB
    __shared__ float gl[TNODES][XPAD];    // 12.5 KB (g tile, reused as z tile)
    __shared__ float sred[TNODES][6], s2red[TNODES][6];
    __shared__ float mubuf[TNODES], ivbuf[TNODES];
    __shared__ float lngl[DIM], lnbl[DIM];
    const int tid = threadIdx.x;
    for (int i = tid; i < DIM * DIM; i += GT) PWl[i / DIM][i % DIM] = PW[i];
    if (tid < DIM) { lngl[tid] = lng[tid]; lnbl[tid] = lnb[tid]; }
    const int tf = tid % 24, tn = tid / 24;
    const int f0 = tf * 4, n0 = tn * 4;
    const float4 pbq = *(const float4*)&pb[f0];
    const int ntiles = (N_NODES + TNODES - 1) / TNODES;

    for (int tile = blockIdx.x; tile < ntiles; tile += gridDim.x) {
        const int base = tile * TNODES;
        __syncthreads();
        for (int i = tid; i < TNODES * DIM; i += GT) {
            const int n = i / DIM, f = i % DIM, gn = base + n;
            gl[n][f] = (gn < N_NODES) ? out[(size_t)gn * DIM + f] : 0.f;
        }
        __syncthreads();
        float acc[4][4] = {};
        for (int k = 0; k < DIM; k += 4) {
            float4 gq[4], wq[4];
            #pragma unroll
            for (int a = 0; a < 4; ++a) gq[a] = *(const float4*)&gl[n0 + a][k];
            #pragma unroll
            for (int b = 0; b < 4; ++b) wq[b] = *(const float4*)&PWl[f0 + b][k];
            #pragma unroll
            for (int a = 0; a < 4; ++a) {
                acc[a][0] += gq[a].x*wq[0].x + gq[a].y*wq[0].y + gq[a].z*wq[0].z + gq[a].w*wq[0].w;
                acc[a][1] += gq[a].x*wq[1].x + gq[a].y*wq[1].y + gq[a].z*wq[1].z + gq[a].w*wq[1].w;
                acc[a][2] += gq[a].x*wq[2].x + gq[a].y*wq[2].y + gq[a].z*wq[2].z + gq[a].w*wq[2].w;
                acc[a][3] += gq[a].x*wq[3].x + gq[a].y*wq[3].y + gq[a].z*wq[3].z + gq[a].w*wq[3].w;
            }
        }
        // z = x + pb + proj
        float4 zq[4];
        #pragma unroll
        for (int a = 0; a < 4; ++a) {
            const int gn = base + n0 + a;
            float4 xq = make_float4(0.f, 0.f, 0.f, 0.f);
            if (gn < N_NODES) xq = *(const float4*)&x[(size_t)gn * DIM + f0];
            zq[a] = make_float4(acc[a][0] + pbq.x + xq.x, acc[a][1] + pbq.y + xq.y,
                                acc[a][2] + pbq.z + xq.z, acc[a][3] + pbq.w + xq.w);
        }
        __syncthreads();   // gl (g) reads done -> reuse as z tile
        #pragma unroll
        for (int a = 0; a < 4; ++a) *(float4*)&gl[n0 + a][f0] = zq[a];
        __syncthreads();
        {   // partial sums: 6 threads per node, 16 elems each
            const int n = tid / 6, j = tid % 6;
            float s = 0.f, s2 = 0.f;
            #pragma unroll
            for (int c = 0; c < 16; ++c) {
                const float v = gl[n][j * 16 + c];
                s += v; s2 += v * v;
            }
            sred[n][j] = s; s2red[n][j] = s2;
        }
        __syncthreads();
        if (tid < TNODES) {
            float s = 0.f, s2 = 0.f;
            #pragma unroll
            for (int j = 0; j < 6; ++j) { s += sred[tid][j]; s2 += s2red[tid][j]; }
            const float mu = s * (1.f / DIM);
            const float var = s2 * (1.f / DIM) - mu * mu;
            mubuf[tid] = mu;
            ivbuf[tid] = rsqrtf(var + LN_EPS);
        }
        __syncthreads();
        for (int i = tid; i < TNODES * 24; i += GT) {
            const int n = i / 24, c = i % 24, gn = base + n;
            if (gn < N_NODES) {
                const float4 v = *(const float4*)&gl[n][c * 4];
                const float mu = mubuf[n], iv = ivbuf[n];
                float4 o;
                o.x = lngl[c*4+0] * (v.x - mu) * iv + lnbl[c*4+0];
                o.y = lngl[c*4+1] * (v.y - mu) * iv + lnbl[c*4+1];
                o.z = lngl[c*4+2] * (v.z - mu) * iv + lnbl[c*4+2];
                o.w = lngl[c*4+3] * (v.w - mu) * iv + lnbl[c*4+3];
                *(float4*)&out[(size_t)gn * DIM + c * 4] = o;
            }
        }
    }
}

// ---------------------------------------------------------------------------
extern "C" void kernel_launch(void* const* d_in, const int* in_sizes, int n_in,
                              void* d_out, int out_size, void* d_ws, size_t ws_size,
                              hipStream_t stream)
{
    const float* x    = (const float*)d_in[0];
    const int*   ei   = (const int*)d_in[1];     // [2, E] int32 (harness-converted)
    const float* W    = (const float*)d_in[2];
    const float* attS = (const float*)d_in[3];
    const float* attD = (const float*)d_in[4];
    const float* gb   = (const float*)d_in[5];
    const float* PW   = (const float*)d_in[6];
    const float* pb   = (const float*)d_in[7];
    const float* lng  = (const float*)d_in[8];
    const float* lnb  = (const float*)d_in[9];
    float* out = (float*)d_out;

    char* ws = (char*)d_ws;
    float* h       = (float*)ws;                                  // N*96 f32 (19.2 MB)
    float* wsrt    = h + (size_t)N_NODES * DIM;                   // E*4 f32 (12.8 MB), 16B-aligned
    float* asrc    = wsrt + (size_t)N_EDGES * 4;                  // N*4 (16B-aligned)
    float* adst    = asrc + N_NODES * HEADS;                      // N*4
    int*   counts  = (int*)(adst + N_NODES * HEADS);              // N
    int*   offsets = counts + N_NODES;                            // N+1
    int*   cursor  = offsets + N_NODES + 1;                       // N
    int*   bsum    = cursor + N_NODES;                            // SCAN_NB
    int*   bpre    = bsum + SCAN_NB;                              // SCAN_NB
    int*   ssrc    = bpre + SCAN_NB;                              // E
    int*   sdst    = ssrc + N_EDGES;                              // E

    hipMemsetAsync(counts, 0, N_NODES * sizeof(int), stream);
    k_hist        <<<(N_EDGES + 255) / 256, 256, 0, stream>>>(ei, counts);
    k_scan_partial<<<SCAN_NB, SCAN_BLK, 0, stream>>>(counts, bsum);
    k_scan_bsums  <<<1, 128, 0, stream>>>(bsum, bpre, offsets);
    k_scan_final  <<<SCAN_NB, SCAN_BLK, 0, stream>>>(counts, bpre, offsets, cursor);
    k_scatter     <<<(N_EDGES + 255) / 256, 256, 0, stream>>>(ei, cursor, ssrc, sdst);
    k_transform   <<<784, GT, 0, stream>>>(x, W, attS, attD, h, asrc, adst);
    k_weights     <<<(N_EDGES + 255) / 256, 256, 0, stream>>>(ssrc, sdst, offsets, asrc, adst, wsrt);
    k_aggregate   <<<(N_NODES * 64 + 255) / 256, 256, 0, stream>>>(offsets, ssrc, wsrt, h, asrc, adst, gb, out);
    k_finalize    <<<784, GT, 0, stream>>>(x, PW, pb, lng, lnb, out);
}